// Round 8
// baseline (321.211 us; speedup 1.0000x reference)
//
#include <hip/hip_runtime.h>
#include <hip/hip_bf16.h>
#include <math.h>

#define N_TOK 16384
#define DIM   2048
#define NE    64
#define TOPK  9

#define G_ROWS   64            // rows per GEMM block (4 row-tiles per wave)
#define NSTEP    64            // kc-granular steps: 32 chunks x 2
#define R_ROWS   32            // rows per router block (4 waves x 8)

typedef short  short8  __attribute__((ext_vector_type(8)));
typedef float  float4_ __attribute__((ext_vector_type(4)));
typedef unsigned short ushort_t;

// ---- inline-asm VMEM loads: invisible to the compiler's waitcnt pass ----
// Volatile asm preserves mutual program order; "=v" outputs stay live from
// issue to use, so the register pipeline cannot be collapsed.
template<int IMM>
__device__ __forceinline__ float4_ gload_f4(const float* sbase, unsigned voff) {
    float4_ d;
    asm volatile("global_load_dwordx4 %0, %1, %2 offset:%3"
                 : "=v"(d) : "v"(voff), "s"(sbase), "i"(IMM));
    return d;
}
template<int IMM>
__device__ __forceinline__ short8 gload_s8(const ushort_t* sbase, unsigned voff) {
    short8 d;
    asm volatile("global_load_dwordx4 %0, %1, %2 offset:%3"
                 : "=v"(d) : "v"(voff), "s"(sbase), "i"(IMM));
    return d;
}
template<int N>
__device__ __forceinline__ void wait_vm_sb() {
    asm volatile("s_waitcnt vmcnt(%0)" :: "i"(N) : "memory");
    __builtin_amdgcn_sched_barrier(0);   // rule #18: pin consumers below the wait
}

__device__ __forceinline__ unsigned pk2(float a, float b) {
    float2 f; f.x = a; f.y = b;
    __hip_bfloat162 h = __float22bfloat162_rn(f);   // low16 = bf16(a)
    unsigned u;
    __builtin_memcpy(&u, &h, 4);
    return u;
}

// 8 fp32 -> bf16 hi frag + bf16 lo frag (2-term split)
__device__ __forceinline__ void cvt8(const float4_ va, const float4_ vb,
                                     short8* h, short8* l) {
    union { short8 s; unsigned u[4]; } H, L;
    const float f[8] = {va[0], va[1], va[2], va[3], vb[0], vb[1], vb[2], vb[3]};
#pragma unroll
    for (int i = 0; i < 4; ++i) {
        const float a = f[2 * i], b = f[2 * i + 1];
        const unsigned p = pk2(a, b);
        H.u[i] = p;
        const float ha = __uint_as_float(p << 16);
        const float hb = __uint_as_float(p & 0xffff0000u);
        L.u[i] = pk2(a - ha, b - hb);
    }
    *h = H.s; *l = L.s;
}

__device__ __forceinline__ void wave_max64_2(float& a, float& b) {
#pragma unroll
    for (int off = 32; off > 0; off >>= 1) {
        const float ax = __shfl_xor(a, off, 64);
        const float bx = __shfl_xor(b, off, 64);
        a = fmaxf(a, ax);
        b = fmaxf(b, bx);
    }
}

__device__ __forceinline__ void wave_sum64_3(float& a, float& b, float& c) {
#pragma unroll
    for (int off = 32; off > 0; off >>= 1) {
        const float ax = __shfl_xor(a, off, 64);
        const float bx = __shfl_xor(b, off, 64);
        const float cx = __shfl_xor(c, off, 64);
        a += ax;
        b += bx;
        c += cx;
    }
}

// ---- prep: Wr|Wn (fp32, D x 64 each) -> B-fragment-ordered bf16 hi/lo ----
// slot s=(kcg*8+ct)*2+t holds 512 bf16: elem l*8+j = B[k=kcg*32+(l>>4)*8+j][n=ct*16+(l&15)]
__global__ __launch_bounds__(256)
void prep_w(const float* __restrict__ Wr, const float* __restrict__ Wn,
            ushort_t* __restrict__ wsW)
{
    const int gid = blockIdx.x * 256 + threadIdx.x;   // [0, 64*8*64)
    const int l   = gid & 63;
    const int ct  = (gid >> 6) & 7;
    const int kcg = gid >> 9;                         // 0..63
    const int n   = ct * 16 + (l & 15);
    const int k0  = kcg * 32 + (l >> 4) * 8;
    const float* src = (n < NE) ? (Wr + n) : (Wn + (n - NE));
    union { short8 s; ushort_t us[8]; } H, L;
#pragma unroll
    for (int j = 0; j < 8; ++j) {
        const float v = src[(size_t)(k0 + j) * NE];
        const unsigned uv = __float_as_uint(v);
        const unsigned hb = (uv + 0x7fffu + ((uv >> 16) & 1u)) & 0xffff0000u;
        const float lo = v - __uint_as_float(hb);
        const unsigned ul = __float_as_uint(lo);
        H.us[j] = (ushort_t)(hb >> 16);
        L.us[j] = (ushort_t)((ul + 0x7fffu + ((ul >> 16) & 1u)) >> 16);
    }
    const size_t s0 = (size_t)(kcg * 8 + ct) * 2;     // slot pair index
    *(short8*)(wsW + s0 * 512 + l * 8)         = H.s;
    *(short8*)(wsW + (s0 + 1) * 512 + l * 8)   = L.s;
}

// ---- one pipeline stage: 4 row-tiles of A (one 32-k half-chunk) + B hi/lo ----
struct Stg { float4_ a0[4]; float4_ a1[4]; short8 h, l; };   // 40 VGPRs

// 10 volatile-asm loads, fixed order: A rt0..rt3 (x2), then B hi, lo.
// voffA(rt,s) = baseA + rt*131072 + s*128 ; voffB(s) = baseB + s*16384
__device__ __forceinline__ void issue_stage(int s,
                                            const float* __restrict__ x_s,
                                            const ushort_t* __restrict__ b_s,
                                            unsigned baseA, unsigned baseB,
                                            Stg& st)
{
    const unsigned va = baseA + (unsigned)s * 128u;
    const unsigned vb = baseB + (unsigned)s * 16384u;
#pragma unroll
    for (int rt = 0; rt < 4; ++rt) {
        st.a0[rt] = gload_f4<0> (x_s, va + (unsigned)rt * 131072u);
        st.a1[rt] = gload_f4<16>(x_s, va + (unsigned)rt * 131072u);
    }
    st.h = gload_s8<0>   (b_s, vb);
    st.l = gload_s8<1024>(b_s, vb);
}

// 4 cvt8 + 12 MFMA: per-output MFMA order identical to previous rounds
__device__ __forceinline__ void compute_stage(const Stg& st, float4_ (&acc)[4]) {
#pragma unroll
    for (int rt = 0; rt < 4; ++rt) {
        short8 ah, al;
        cvt8(st.a0[rt], st.a1[rt], &ah, &al);
        acc[rt] = __builtin_amdgcn_mfma_f32_16x16x32_bf16(ah, st.h, acc[rt], 0, 0, 0);
        acc[rt] = __builtin_amdgcn_mfma_f32_16x16x32_bf16(al, st.h, acc[rt], 0, 0, 0);
        acc[rt] = __builtin_amdgcn_mfma_f32_16x16x32_bf16(ah, st.l, acc[rt], 0, 0, 0);
    }
}

// ---- GEMM: x[16384x2048] @ [Wr|Wn] -> logits[16384x128] (raw|noise) ----
// Block = 64 rows x 64 cols; wave w owns col-tile (colhalf*4+w), 4 row-tiles.
// 3-deep kc-granular register pipeline: 30 loads in flight, vmcnt(20);
// per-stage compute (~4 cvt8 + 12 MFMA) exceeds L2 latency -> ILP-hidden.
__global__ __launch_bounds__(256, 2)
void gemm_logits(const float* __restrict__ x,
                 const ushort_t* __restrict__ wsW,
                 float* __restrict__ logits)
{
    const int t    = threadIdx.x;
    const int lane = t & 63;
    const int w    = t >> 6;
    const int c4   = lane & 15;
    const int q    = lane >> 4;
    const int rowb = blockIdx.x >> 1;
    const int colh = blockIdx.x & 1;
    const int row0 = rowb * G_ROWS;
    const int ct   = colh * 4 + w;     // global col-tile 0..7

    const unsigned baseA = (unsigned)(((row0 + c4) * DIM + q * 8) * 4);
    const unsigned baseB = (unsigned)(ct * 2048 + lane * 16);

    float4_ acc[4];
#pragma unroll
    for (int rt = 0; rt < 4; ++rt) acc[rt] = (float4_)(0.f);

    Stg sX, sY, sZ;
    issue_stage(0, x, wsW, baseA, baseB, sX);
    issue_stage(1, x, wsW, baseA, baseB, sY);
    issue_stage(2, x, wsW, baseA, baseB, sZ);

#pragma unroll 1
    for (int s = 0; s < NSTEP - 4; s += 3) {
        wait_vm_sb<20>();                    // stage s retired
        compute_stage(sX, acc);
        issue_stage(s + 3, x, wsW, baseA, baseB, sX);
        wait_vm_sb<20>();                    // stage s+1 retired
        compute_stage(sY, acc);
        issue_stage(s + 4, x, wsW, baseA, baseB, sY);
        wait_vm_sb<20>();                    // stage s+2 retired
        compute_stage(sZ, acc);
        issue_stage(s + 5, x, wsW, baseA, baseB, sZ);
    }
    // tail: steps 60..63
    wait_vm_sb<20>();
    compute_stage(sX, acc);
    issue_stage(NSTEP - 1, x, wsW, baseA, baseB, sX);
    wait_vm_sb<20>();
    compute_stage(sY, acc);
    wait_vm_sb<10>();
    compute_stage(sZ, acc);
    wait_vm_sb<0>();
    compute_stage(sX, acc);

    // store: C/D mapping col=lane&15, row=(lane>>4)*4+reg
    const int colg = ct * 16 + c4;           // 0..127 (raw|noise)
#pragma unroll
    for (int rt = 0; rt < 4; ++rt)
#pragma unroll
        for (int v = 0; v < 4; ++v) {
            const int row = rt * 16 + q * 4 + v;
            logits[(size_t)(row0 + row) * 128 + colg] = acc[rt][v];
        }
}

// ---- router: per-row top-k / softmaxes / load-balancing stats ----
__global__ __launch_bounds__(256)
void router(const float* __restrict__ logits,
            const float* __restrict__ br,
            const float* __restrict__ bn,
            const float* __restrict__ noise_eps,
            const float* __restrict__ gumbel,
            float* __restrict__ out)
{
    __shared__ float red[512];
    const int t    = threadIdx.x;
    const int lane = t & 63;
    const int w    = t >> 6;
    const int row0 = blockIdx.x * R_ROWS + w * 8;

    const float br_l = br[lane];
    const float bn_l = bn[lane];

    // prefetch all 8 rows x 4 streams (issues 32 independent loads)
    float rawv[8], nlv[8], epsv[8], gumv[8];
#pragma unroll
    for (int r = 0; r < 8; ++r) {
        const size_t row = (size_t)(row0 + r);
        rawv[r] = logits[row * 128 + lane];
        nlv[r]  = logits[row * 128 + 64 + lane];
        epsv[r] = noise_eps[row * NE + lane];
        gumv[r] = gumbel  [row * NE + lane];
    }

    float imp_acc = 0.f, load_acc = 0.f;
    float* out_em   = out;
    float* out_rp   = out + (size_t)N_TOK * NE;
    float* out_imp  = out + (size_t)2 * N_TOK * NE;
    float* out_load = out_imp + NE;

#pragma unroll 2
    for (int r = 0; r < 8; ++r) {
        const int row = row0 + r;
        const float raw = rawv[r] + br_l;
        const float nl  = nlv[r]  + bn_l;
        const float sd = fmaxf(nl, 0.f) + log1pf(expf(-fabsf(nl))) + 0.01f;
        const float noisy = fmaf(epsv[r], sd, raw);

        // ---- threshold = 9th largest via ballot binary search (bit-exact) ----
        const unsigned uk  = __float_as_uint(noisy);
        const unsigned key = uk ^ ((uk & 0x80000000u) ? 0xFFFFFFFFu : 0x80000000u);
        unsigned res = 0;
#pragma unroll
        for (int bit = 31; bit >= 0; --bit) {
            const unsigned cand = res | (1u << bit);
            const int cnt = __popcll(__ballot(key >= cand));
            if (cnt >= TOPK) res = cand;
        }
        const float thr  = __uint_as_float(res ^ ((res & 0x80000000u) ? 0x80000000u : 0xFFFFFFFFu));
        const float hard = (key >= res) ? 1.f : 0.f;

        // fused reductions: one dual-max chain, one triple-sum chain
        const float g = noisy + gumv[r];
        float mg = g, mr = raw;
        wave_max64_2(mg, mr);

        const float eg = expf(g - mg);
        const float en = expf(noisy - thr);   // softmax shift-invariant
        const float er = expf(raw - mr);
        float sg = eg, sn = en, sr = er;
        wave_sum64_3(sg, sn, sr);

        const float ms = eg / sg;
        const float em = (hard - ms) + ms;
        const float rp = en / sn;
        imp_acc += er / sr;

        const float z = (thr - raw) / sd;
        load_acc += 0.5f * erfcf(z * 45.254833995939045f);

        out_em[(size_t)row * NE + lane] = em;
        out_rp[(size_t)row * NE + lane] = rp;
    }

    red[w * 64 + lane]       = imp_acc;
    red[256 + w * 64 + lane] = load_acc;
    __syncthreads();
    if (w == 0) {
        const float s1 = red[lane] + red[64 + lane] + red[128 + lane] + red[192 + lane];
        const float s2 = red[256 + lane] + red[320 + lane] + red[384 + lane] + red[448 + lane];
        atomicAdd(&out_imp[lane], s1);
        atomicAdd(&out_load[lane], s2);
    }
}

extern "C" void kernel_launch(void* const* d_in, const int* in_sizes, int n_in,
                              void* d_out, int out_size, void* d_ws, size_t ws_size,
                              hipStream_t stream)
{
    const float* x         = (const float*)d_in[0];
    const float* Wr        = (const float*)d_in[1];
    const float* br        = (const float*)d_in[2];
    const float* Wn        = (const float*)d_in[3];
    const float* bn        = (const float*)d_in[4];
    const float* noise_eps = (const float*)d_in[5];
    const float* gumbel    = (const float*)d_in[6];
    float* out = (float*)d_out;

    ushort_t* wsW = (ushort_t*)d_ws;                       // 1 MB B-fragments
    float* logits = (float*)((char*)d_ws + (1 << 20));     // 8 MB raw|noise

    (void)hipMemsetAsync((char*)d_out + (size_t)2 * N_TOK * NE * sizeof(float), 0,
                         2 * NE * sizeof(float), stream);
    prep_w<<<128, 256, 0, stream>>>(Wr, Wn, wsW);
    gemm_logits<<<(N_TOK / G_ROWS) * 2, 256, 0, stream>>>(x, wsW, logits);
    router<<<N_TOK / R_ROWS, 256, 0, stream>>>(logits, br, bn, noise_eps, gumbel, out);
}